// Round 13
// baseline (85.720 us; speedup 1.0000x reference)
//
#include <hip/hip_runtime.h>

// Problem constants (fixed by reference)
#define CIN     32
#define COUT    64
#define OUT_DIM 1024
#define RS4     1024           // float4 per (.,c) row (4096 floats)

// out[b,o,p] = (1/sqrt(32)) * sum_{c,k} x[b,c,4p+k] * w[o,c,4p+k]
//
// v15: T3+T4 (counted-vmcnt deep pipeline) on v13's byte budget. v13/v14
// showed the last wall is HBM duty cycle: __syncthreads' vmcnt(0) drain
// idles every CU for the delivery tail of each chunk, in phase chip-wide
// (~60% HBM duty -> 16.7 us vs ~8 us ideal). Fix per the guide's catalog:
// never drain vmcnt to 0 in the loop. 8 c-chunks, THREE 32 KB LDS buffer
// pairs (96 KB), 2-chunk-deep prefetch; each wave stages exactly 4
// global_load_lds per chunk so chunk boundaries are vmcnt-countable:
//
//   stage(0); stage(1);
//   for ci in 0..7:
//     s_waitcnt vmcnt(4)   // chunk ci landed; ci+1 stays IN FLIGHT
//     s_barrier            // all waves waited their own counter
//     stage(ci+2)          // refill the pipe (buf (ci+2)%3: its readers
//                          //   were compute(ci-1), before this barrier)
//     compute(ci)          // LDS-only
//
// HBM always has >=1 full chunk queued per CU -> no breathing; expected
// kernel ~= max(HBM 44-48 MB ~7.5 us, LDS/VALU ~4-5 us) + ramp ~= 9-12 us.
// Geometry as v13: o-tile 16, all 16 b, 16-patch columns; grid 256 =
// 4 og x 64 pc, 1 block/CU; swizzle: og-siblings of a pc share an XCD.
__global__ __launch_bounds__(512, 2) void nolc1d_kernel(
    const float* __restrict__ x,
    const float* __restrict__ w,
    float* __restrict__ out)
{
    const int bid = blockIdx.x;
    const int xcd = bid & 7;
    const int m   = bid >> 3;               // 0..31
    const int og  = m & 3;                  // o-group 0..3 (16 o each)
    const int pc  = xcd * 8 + (m >> 2);     // patch-chunk 0..63 (16 p each)
    const int o0  = og * 16;
    const int pf0 = pc * 16;                // f4 (=patch) column base

    const int t    = threadIdx.x;           // = oq*128 + g*32 + cs*16 + p
    const int lane = t & 63;
    const int wv   = t >> 6;                // wave 0..7
    const int p    = t & 15;                // patch within tile
    const int cs   = (t >> 4) & 1;          // c-split (2-way)
    const int g    = (t >> 5) & 3;          // b-quad (b = 4g+bi)
    const int oq   = t >> 7;                // o-quad (o = o0+4oq+oi)

    // [buf][(hi*4 + cl)*16 + q]: hi = ol (w) / b (x), cl = c in chunk,
    // q = f4 column. 1024 f4 = 16 KB per buffer per operand; 96 KB total.
    __shared__ float4 wls[3][1024];
    __shared__ float4 xls[3][1024];

    const float4* __restrict__ x4 = (const float4*)x;
    const float4* __restrict__ w4 = (const float4*)w;

    const int r4 = lane >> 4;               // cl 0..3
    const int q  = lane & 15;

    // Stage chunk ci (c = 4ci..4ci+3) into buffer `buf`: 4 instrs/wave
    // (2 w + 2 x), 1 KB each. Instr s = wv*2+i stages hi = s: 4 rows
    // (cl=0..3) x 256 B. LDS dest wave-uniform + lane*16 (linear); global
    // source lane -> row (hi=s, cl=r4), col q.
    auto stage = [&](int buf, int ci) {
        #pragma unroll
        for (int i = 0; i < 2; ++i) {
            const int s = wv * 2 + i;       // hi 0..15
            const int c = ci * 4 + r4;
            const float4* srcw =
                &w4[((o0 + s) * CIN + c) * RS4 + pf0 + q];
            __builtin_amdgcn_global_load_lds(
                (const __attribute__((address_space(1))) void*)srcw,
                (__attribute__((address_space(3))) void*)&wls[buf][s * 64],
                16, 0, 0);
            const float4* srcx =
                &x4[(s * CIN + c) * RS4 + pf0 + q];
            __builtin_amdgcn_global_load_lds(
                (const __attribute__((address_space(1))) void*)srcx,
                (__attribute__((address_space(3))) void*)&xls[buf][s * 64],
                16, 0, 0);
        }
    };

    float acc[4][4] = {};                   // [bi][oi], carried over ci

    stage(0, 0);                            // 4 in flight
    stage(1, 1);                            // 8 in flight

    #pragma unroll 1
    for (int ci = 0; ci < 8; ++ci) {
        // Wait for chunk ci only (own wave's oldest 4); keep ci+1 in
        // flight across the barrier. Last iter: nothing behind, drain.
        if (ci < 7) asm volatile("s_waitcnt vmcnt(4)" ::: "memory");
        else        asm volatile("s_waitcnt vmcnt(0)" ::: "memory");
        __builtin_amdgcn_s_barrier();       // all waves' chunk-ci landed
        if (ci < 6) stage((ci + 2) % 3, ci + 2);   // keep pipe 2 deep
        const int buf = ci % 3;
        // compute: LDS only. This thread's c's: cl = cs*2 + jj.
        // x/w reads: 256 B runs per half-wave, 2-way broadcast -> free.
        #pragma unroll
        for (int jj = 0; jj < 2; ++jj) {
            const int cl = cs * 2 + jj;
            float4 xv[4], wq[4];
            #pragma unroll
            for (int bi = 0; bi < 4; ++bi)
                xv[bi] = xls[buf][((g * 4 + bi) * 4 + cl) * 16 + p];
            #pragma unroll
            for (int oi = 0; oi < 4; ++oi)
                wq[oi] = wls[buf][((oq * 4 + oi) * 4 + cl) * 16 + p];
            #pragma unroll
            for (int bi = 0; bi < 4; ++bi)
                #pragma unroll
                for (int oi = 0; oi < 4; ++oi)
                    acc[bi][oi] += xv[bi].x * wq[oi].x + xv[bi].y * wq[oi].y +
                                   xv[bi].z * wq[oi].z + xv[bi].w * wq[oi].w;
        }
        // No trailing barrier: next iter's (own-vmcnt wait + barrier)
        // is the handoff; buffer overwritten only 3 chunks later.
    }

    // c-reduction: partner t^16 (same oq,g,p; cs^1) holds the other half.
    #pragma unroll
    for (int bi = 0; bi < 4; ++bi)
        #pragma unroll
        for (int oi = 0; oi < 4; ++oi)
            acc[bi][oi] += __shfl_xor(acc[bi][oi], 16, 64);

    const float scale = 0.17677669529663687f;  // 1/sqrt(32)
    if (cs == 0) {
        // lanes p=0..15 -> 64 B contiguous store per (bi,oi) group;
        // single writer per line.
        #pragma unroll
        for (int bi = 0; bi < 4; ++bi)
            #pragma unroll
            for (int oi = 0; oi < 4; ++oi)
                out[((size_t)(4 * g + bi) * COUT + o0 + 4 * oq + oi) * OUT_DIM
                    + pf0 + p] = acc[bi][oi] * scale;
    }
}

extern "C" void kernel_launch(void* const* d_in, const int* in_sizes, int n_in,
                              void* d_out, int out_size, void* d_ws, size_t ws_size,
                              hipStream_t stream) {
    const float* x = (const float*)d_in[0];   // [16][32][4096] fp32
    const float* w = (const float*)d_in[1];   // [64][32][4096] fp32
    float* out = (float*)d_out;               // [16][64][1024] fp32

    nolc1d_kernel<<<dim3(256), dim3(512), 0, stream>>>(x, w, out);
}